// Round 4
// baseline (122.311 us; speedup 1.0000x reference)
//
#include <hip/hip_runtime.h>

#define Hh 384
#define Ww 384
#define Bb 4
#define NN 64
#define HW (Hh*Ww)
#define NSEG (NN-1)
#define RENDER_BLOCKS 576            // per batch
#define TOTAL_RENDER (RENDER_BLOCKS*Bb)

// ---------------- conv (separable DoG) -> gimg [B][H][W][2]; also zeroes acc
#define TILE 32
#define HALO 8
__global__ __launch_bounds__(256) void k_conv(const float* __restrict__ img,
        float2* __restrict__ gimg, unsigned long long* __restrict__ acc,
        unsigned int* __restrict__ count) {
    __shared__ float sIn[TILE+2*HALO][TILE+2*HALO];      // 48x48
    __shared__ float sColG[TILE+2*HALO][TILE];
    __shared__ float sColD[TILE+2*HALO][TILE];
    __shared__ float gtap[17], dtap[17];
    const int b  = blockIdx.z;
    const int x0 = blockIdx.x * TILE;
    const int y0 = blockIdx.y * TILE;
    const int tid = threadIdx.x;
    if (blockIdx.x == 0 && blockIdx.y == 0 && blockIdx.z == 0 && tid == 0) {
        *acc = 0ULL; *count = 0u;    // reset render reduction state every call
    }
    if (tid == 0) {
        float s = 0.f;
        for (int i = 0; i < 17; ++i) {
            float xv = (float)(i - 8);
            float e  = expf(-0.5f * (xv*0.5f)*(xv*0.5f));
            gtap[i] = e; s += e;
            dtap[i] = -(xv*0.25f) * e;
        }
        for (int i = 0; i < 17; ++i) gtap[i] /= s;
    }
    const float* im = img + b*HW;
    for (int idx = tid; idx < 48*48; idx += blockDim.x) {
        int r = idx / 48, c = idx % 48;
        int gx = x0 + r - HALO, gy = y0 + c - HALO;
        float v = 0.f;
        if (gx >= 0 && gx < Hh && gy >= 0 && gy < Ww) v = im[gx*Ww + gy];
        sIn[r][c] = v;
    }
    __syncthreads();
    for (int idx = tid; idx < 48*TILE; idx += blockDim.x) {
        int r = idx / TILE, c = idx % TILE;
        float ag = 0.f, ad = 0.f;
#pragma unroll
        for (int k = 0; k < 17; ++k) {
            float v = sIn[r][c+k];
            ag += gtap[k]*v;
            ad += dtap[k]*v;
        }
        sColG[r][c] = ag; sColD[r][c] = ad;
    }
    __syncthreads();
    float2* gg = gimg + (size_t)b*HW;
    for (int idx = tid; idx < TILE*TILE; idx += blockDim.x) {
        int xo = idx / TILE, c = idx % TILE;
        float a0 = 0.f, a1 = 0.f;
#pragma unroll
        for (int k = 0; k < 17; ++k) {
            a0 += dtap[k]*sColG[xo+k][c];
            a1 += gtap[k]*sColD[xo+k][c];
        }
        int gx = x0+xo, gy = y0+c;
        gg[gx*Ww+gy] = make_float2(10.f*a0, 10.f*a1);
    }
}

// ------- snake (Ainv build + 20 steps) + radial widths + segment prep ------
__global__ __launch_bounds__(256) void k_snake(const float2* __restrict__ gimg,
                        const float* __restrict__ pred, const float* __restrict__ init,
                        float4* __restrict__ pA, float4* __restrict__ pB) {
    __shared__ float sA[NN][NN+1];
    __shared__ float sd[NN], su1[NN], su2[NN], sb1[NN], sL1[NN], sL2[NN], sdinv[NN];
    __shared__ float2 stxy[NN];
    __shared__ int   sRh[NN], sRo[NN];
    __shared__ float swf[NN];
    const int b = blockIdx.x;
    const int tid = threadIdx.x;
    const int i = tid >> 2;
    const int q = tid & 3;

    // ---- (I + 0.1*A)^-1 via banded LU ----
    if (tid == 0) {
        for (int k = 0; k < NN; ++k) { sd[k] = 0.f; su1[k] = 0.f; su2[k] = 0.f; }
        for (int k = 0; k < NN-1; ++k) { sd[k] += 0.01f; sd[k+1] += 0.01f; su1[k] -= 0.01f; }
        for (int k = 0; k < NN-2; ++k) {
            sd[k] += 0.01f; sd[k+1] += 0.04f; sd[k+2] += 0.01f;
            su1[k] -= 0.02f; su1[k+1] -= 0.02f; su2[k] += 0.01f;
        }
        for (int k = 0; k < NN; ++k) {
            sd[k]  = 1.0f + 0.1f*sd[k];
            su1[k] = 0.1f*su1[k];
            su2[k] = 0.1f*su2[k];
            sb1[k] = su1[k];
        }
        for (int k = 0; k < NN; ++k) {
            float di = sd[k];
            if (k+1 < NN) {
                float l = sb1[k]/di; sL1[k] = l;
                sd[k+1] -= l*su1[k];
                if (k+2 < NN) su1[k+1] -= l*su2[k];
            }
            if (k+2 < NN) {
                float l = su2[k]/di; sL2[k] = l;
                sb1[k+1] -= l*su1[k];
                sd[k+2]  -= l*su2[k];
            }
        }
    }
    __syncthreads();
    if (tid < NN) sdinv[tid] = 1.0f/sd[tid];
    __syncthreads();
    if (tid < NN) {
        const int t = tid;
        float y[NN], x[NN];
#pragma unroll
        for (int k = 0; k < NN; ++k) {
            float v = (k == t) ? 1.0f : 0.0f;
            if (k >= 1) v -= sL1[k-1]*y[k-1];
            if (k >= 2) v -= sL2[k-2]*y[k-2];
            y[k] = v;
        }
#pragma unroll
        for (int kk = 0; kk < NN; ++kk) {
            int k = NN-1-kk;
            float v = y[k];
            if (k+1 < NN) v -= su1[k]*x[k+1];
            if (k+2 < NN) v -= su2[k]*x[k+2];
            x[k] = v*sdinv[k];
        }
        for (int k = 0; k < NN; ++k) sA[k][t] = x[k];
    }
    __syncthreads();

    float ar[16];
#pragma unroll
    for (int k = 0; k < 16; ++k) ar[k] = sA[i][q*16 + k];

    float px = init[(b*NN + i)*2 + 0];
    float py = init[(b*NN + i)*2 + 1];
    const float2* g = gimg + (size_t)b*HW;

    for (int s = 0; s < 20; ++s) {
        float x = fminf(fmaxf(px, 0.f), (float)(Hh-1));
        float y = fminf(fmaxf(py, 0.f), (float)(Ww-1));
        int x0i = (int)floorf(x); x0i = min(max(x0i, 0), Hh-2);
        int y0i = (int)floorf(y); y0i = min(max(y0i, 0), Ww-2);
        float fx = x - (float)x0i, fy = y - (float)y0i;
        int base = x0i*Ww + y0i;
        float2 v00 = g[base],    v01 = g[base+1];
        float2 v10 = g[base+Ww], v11 = g[base+Ww+1];
        float t0x = v00.x*(1.f-fy) + v01.x*fy;
        float t0y = v00.y*(1.f-fy) + v01.y*fy;
        float b0x = v10.x*(1.f-fy) + v11.x*fy;
        float b0y = v10.y*(1.f-fy) + v11.y*fy;
        float f0 = t0x*(1.f-fx) + b0x*fx;
        float f1 = t0y*(1.f-fx) + b0y*fx;
        if (q == 0) stxy[i] = make_float2(px + 0.1f*f0, py + 0.1f*f1);
        __syncthreads();
        float ax = 0.f, ay = 0.f;
#pragma unroll
        for (int k = 0; k < 16; ++k) {
            float2 tv = stxy[q*16 + k];
            ax = fmaf(ar[k], tv.x, ax);
            ay = fmaf(ar[k], tv.y, ay);
        }
        ax += __shfl_xor(ax, 1); ay += __shfl_xor(ay, 1);
        ax += __shfl_xor(ax, 2); ay += __shfl_xor(ay, 2);
        px = ax; py = ay;
        __syncthreads();
    }
    // publish final positions
    if (q == 0) stxy[i] = make_float2(px, py);
    if (tid < NN) { sRh[tid] = 0x7fffffff; sRo[tid] = 0x7fffffff; }
    __syncthreads();

    // ---- radial widths: 2304 (node,angle) rays, 9 per thread ----
    const float* p = pred + (size_t)b*HW;
#pragma unroll
    for (int k = 0; k < 9; ++k) {
        int pair = tid + k*256;
        int node = pair / 36, ang = pair - node*36;
        float sx = rintf(stxy[node].x);
        float sy = rintf(stxy[node].y);
        float th = (float)(10*ang) * 0.017453292519943295f;
        float c = cosf(th), s = sinf(th);
        for (int r = 1; r < Hh; ++r) {
            float rf = (float)r;
            int xi = (int)floorf(sx + rf*c);
            int yi = (int)floorf(sy + rf*s);
            bool inb = (xi >= 0) & (xi < Hh) & (yi >= 0) & (yi < Ww);
            if (!inb) { atomicMin(&sRo[node], r); break; }
            if (p[xi*Ww + yi] > 0.f) { atomicMin(&sRh[node], r); break; }
        }
    }
    __syncthreads();
    if (tid < NN) {
        int Rh = sRh[tid], Ro = sRo[tid];
        swf[tid] = (Rh != 0x7fffffff && Rh <= Ro) ? (float)(Rh - 1) : 0.f;
    }
    __syncthreads();

    // ---- segment prep ----
    if (tid < NSEG) {
        float2 P0 = stxy[tid], P1 = stxy[tid+1];
        float vx = P1.x - P0.x, vy = P1.y - P0.y;
        float vv = vx*vx + vy*vy + 1e-8f;
        float w0 = swf[tid], w1 = swf[tid+1];
        pA[b*NSEG + tid] = make_float4(P0.x, P0.y, vx, vy);
        pB[b*NSEG + tid] = make_float4(1.0f/vv, w0, w1 - w0, 0.f);
    }
}

// ---------------- render + fused deterministic final reduction -------------
__global__ __launch_bounds__(256) void k_render(const float* __restrict__ pred,
                        const float4* __restrict__ pAg, const float4* __restrict__ pBg,
                        unsigned long long* __restrict__ acc, unsigned int* __restrict__ count,
                        float* __restrict__ out) {
    __shared__ float red[256];
    const int b = blockIdx.y;
    const int tid = threadIdx.x;
    const int pix = blockIdx.x*256 + tid;
    const float fx = (float)(pix / Ww), fy = (float)(pix % Ww);
    const float4* pA = pAg + b*NSEG;
    const float4* pB = pBg + b*NSEG;
    float m1 = 1e30f, m2 = 1e30f;
    for (int s2 = 0; s2 < NSEG; ++s2) {
        const float4 A = pA[s2];     // p0x p0y vx vy (wave-uniform -> scalar)
        const float4 Bv = pB[s2];    // invvv w0 dw -
        float dx = fx - A.x, dy = fy - A.y;
        float t = fmaf(dy, A.w, dx*A.z) * Bv.x;
        t = fminf(fmaxf(t, 0.f), 1.f);
        float ex = fmaf(-t, A.z, dx);
        float ey = fmaf(-t, A.w, dy);
        float d2 = fmaf(ex, ex, fmaf(ey, ey, 1e-12f));
        float wt = fmaf(t, Bv.z, Bv.y);
        m1 = fminf(m1, d2);
        m2 = fminf(m2, fmaf(-wt, wt, d2));
    }
    float dmap = fminf(sqrtf(m1), 15.f);
    float pm = (m2 <= 0.f) ? 1.f : 0.f;
    float pv = pred[(size_t)b*HW + pix];
    float sg = 1.f/(1.f + expf(-pv));
    float t1 = pv - dmap, t2 = sg - pm;
    red[tid] = t1*t1 + t2*t2;
    __syncthreads();
    for (int off = 128; off > 0; off >>= 1) {
        if (tid < off) red[tid] += red[tid+off];
        __syncthreads();
    }
    if (tid == 0) {
        // fixed-point (2^24) integer accumulation: order-independent => deterministic
        unsigned long long q = (unsigned long long)__double2ll_rn((double)red[0] * 16777216.0);
        atomicAdd(acc, q);
        __threadfence();
        unsigned int done = atomicAdd(count, 1u);
        if (done == TOTAL_RENDER - 1) {
            unsigned long long total = atomicAdd(acc, 0ULL);
            out[0] = (float)((double)total * (1.0/16777216.0) / (double)((size_t)Bb*HW));
        }
    }
}

extern "C" void kernel_launch(void* const* d_in, const int* in_sizes, int n_in,
                              void* d_out, int out_size, void* d_ws, size_t ws_size,
                              hipStream_t stream) {
    const float* pred = (const float*)d_in[0];   // [4,1,384,384] f32
    const float* init = (const float*)d_in[1];   // [4,64,2] f32
    float* out = (float*)d_out;
    char* ws = (char*)d_ws;
    // ws: pA @0 (4*63*16=4032B) | pB @4096 | acc @8192 | count @8200 | gimg @28672
    float4* pA = (float4*)(ws);
    float4* pB = (float4*)(ws + 4096);
    unsigned long long* acc = (unsigned long long*)(ws + 8192);
    unsigned int* count     = (unsigned int*)(ws + 8200);
    float2* gimg = (float2*)(ws + 28672);

    k_conv  <<<dim3(12,12,4),           dim3(256), 0, stream>>>(pred, gimg, acc, count);
    k_snake <<<dim3(4),                 dim3(256), 0, stream>>>(gimg, pred, init, pA, pB);
    k_render<<<dim3(RENDER_BLOCKS,Bb),  dim3(256), 0, stream>>>(pred, pA, pB, acc, count, out);
}

// Round 5
// 69.082 us; speedup vs baseline: 1.7705x; 1.7705x over previous
//
#include <hip/hip_runtime.h>

#define Hh 384
#define Ww 384
#define Bb 4
#define NN 64
#define HW (Hh*Ww)
#define NSEG (NN-1)
#define TPB 24                        // 24x24 tiles of 16x16
#define NTILES (TPB*TPB)              // 576 per batch

// ---------------- conv (separable DoG) -> gimg [B][H][W][2] ----------------
#define TILE 32
#define HALO 8
__global__ __launch_bounds__(256) void k_conv(const float* __restrict__ img,
        float2* __restrict__ gimg) {
    __shared__ float sIn[TILE+2*HALO][TILE+2*HALO];      // 48x48
    __shared__ float sColG[TILE+2*HALO][TILE];
    __shared__ float sColD[TILE+2*HALO][TILE];
    __shared__ float gtap[17], dtap[17];
    const int b  = blockIdx.z;
    const int x0 = blockIdx.x * TILE;
    const int y0 = blockIdx.y * TILE;
    const int tid = threadIdx.x;
    if (tid == 0) {
        float s = 0.f;
        for (int i = 0; i < 17; ++i) {
            float xv = (float)(i - 8);
            float e  = expf(-0.5f * (xv*0.5f)*(xv*0.5f));
            gtap[i] = e; s += e;
            dtap[i] = -(xv*0.25f) * e;
        }
        for (int i = 0; i < 17; ++i) gtap[i] /= s;
    }
    const float* im = img + b*HW;
    for (int idx = tid; idx < 48*48; idx += blockDim.x) {
        int r = idx / 48, c = idx % 48;
        int gx = x0 + r - HALO, gy = y0 + c - HALO;
        float v = 0.f;
        if (gx >= 0 && gx < Hh && gy >= 0 && gy < Ww) v = im[gx*Ww + gy];
        sIn[r][c] = v;
    }
    __syncthreads();
    for (int idx = tid; idx < 48*TILE; idx += blockDim.x) {
        int r = idx / TILE, c = idx % TILE;
        float ag = 0.f, ad = 0.f;
#pragma unroll
        for (int k = 0; k < 17; ++k) {
            float v = sIn[r][c+k];
            ag += gtap[k]*v;
            ad += dtap[k]*v;
        }
        sColG[r][c] = ag; sColD[r][c] = ad;
    }
    __syncthreads();
    float2* gg = gimg + (size_t)b*HW;
    for (int idx = tid; idx < TILE*TILE; idx += blockDim.x) {
        int xo = idx / TILE, c = idx % TILE;
        float a0 = 0.f, a1 = 0.f;
#pragma unroll
        for (int k = 0; k < 17; ++k) {
            a0 += dtap[k]*sColG[xo+k][c];
            a1 += gtap[k]*sColD[xo+k][c];
        }
        int gx = x0+xo, gy = y0+c;
        gg[gx*Ww+gy] = make_float2(10.f*a0, 10.f*a1);
    }
}

// ------- snake (Ainv build + 20 steps) + radial widths + segment prep ------
__global__ __launch_bounds__(256) void k_snake(const float2* __restrict__ gimg,
                        const float* __restrict__ pred, const float* __restrict__ init,
                        float4* __restrict__ pA, float4* __restrict__ pB) {
    __shared__ float sA[NN][NN+1];
    __shared__ float sd[NN], su1[NN], su2[NN], sb1[NN], sL1[NN], sL2[NN], sdinv[NN];
    __shared__ float2 stxy[NN];
    __shared__ int   sRh[NN], sRo[NN];
    __shared__ float swf[NN];
    const int b = blockIdx.x;
    const int tid = threadIdx.x;
    const int i = tid >> 2;
    const int q = tid & 3;

    if (tid == 0) {
        for (int k = 0; k < NN; ++k) { sd[k] = 0.f; su1[k] = 0.f; su2[k] = 0.f; }
        for (int k = 0; k < NN-1; ++k) { sd[k] += 0.01f; sd[k+1] += 0.01f; su1[k] -= 0.01f; }
        for (int k = 0; k < NN-2; ++k) {
            sd[k] += 0.01f; sd[k+1] += 0.04f; sd[k+2] += 0.01f;
            su1[k] -= 0.02f; su1[k+1] -= 0.02f; su2[k] += 0.01f;
        }
        for (int k = 0; k < NN; ++k) {
            sd[k]  = 1.0f + 0.1f*sd[k];
            su1[k] = 0.1f*su1[k];
            su2[k] = 0.1f*su2[k];
            sb1[k] = su1[k];
        }
        for (int k = 0; k < NN; ++k) {
            float di = sd[k];
            if (k+1 < NN) {
                float l = sb1[k]/di; sL1[k] = l;
                sd[k+1] -= l*su1[k];
                if (k+2 < NN) su1[k+1] -= l*su2[k];
            }
            if (k+2 < NN) {
                float l = su2[k]/di; sL2[k] = l;
                sb1[k+1] -= l*su1[k];
                sd[k+2]  -= l*su2[k];
            }
        }
    }
    __syncthreads();
    if (tid < NN) sdinv[tid] = 1.0f/sd[tid];
    __syncthreads();
    if (tid < NN) {
        const int t = tid;
        float y[NN], x[NN];
#pragma unroll
        for (int k = 0; k < NN; ++k) {
            float v = (k == t) ? 1.0f : 0.0f;
            if (k >= 1) v -= sL1[k-1]*y[k-1];
            if (k >= 2) v -= sL2[k-2]*y[k-2];
            y[k] = v;
        }
#pragma unroll
        for (int kk = 0; kk < NN; ++kk) {
            int k = NN-1-kk;
            float v = y[k];
            if (k+1 < NN) v -= su1[k]*x[k+1];
            if (k+2 < NN) v -= su2[k]*x[k+2];
            x[k] = v*sdinv[k];
        }
        for (int k = 0; k < NN; ++k) sA[k][t] = x[k];
    }
    __syncthreads();

    float ar[16];
#pragma unroll
    for (int k = 0; k < 16; ++k) ar[k] = sA[i][q*16 + k];

    float px = init[(b*NN + i)*2 + 0];
    float py = init[(b*NN + i)*2 + 1];
    const float2* g = gimg + (size_t)b*HW;

    for (int s = 0; s < 20; ++s) {
        float x = fminf(fmaxf(px, 0.f), (float)(Hh-1));
        float y = fminf(fmaxf(py, 0.f), (float)(Ww-1));
        int x0i = (int)floorf(x); x0i = min(max(x0i, 0), Hh-2);
        int y0i = (int)floorf(y); y0i = min(max(y0i, 0), Ww-2);
        float fx = x - (float)x0i, fy = y - (float)y0i;
        int base = x0i*Ww + y0i;
        float2 v00 = g[base],    v01 = g[base+1];
        float2 v10 = g[base+Ww], v11 = g[base+Ww+1];
        float t0x = v00.x*(1.f-fy) + v01.x*fy;
        float t0y = v00.y*(1.f-fy) + v01.y*fy;
        float b0x = v10.x*(1.f-fy) + v11.x*fy;
        float b0y = v10.y*(1.f-fy) + v11.y*fy;
        float f0 = t0x*(1.f-fx) + b0x*fx;
        float f1 = t0y*(1.f-fx) + b0y*fx;
        if (q == 0) stxy[i] = make_float2(px + 0.1f*f0, py + 0.1f*f1);
        __syncthreads();
        float ax = 0.f, ay = 0.f;
#pragma unroll
        for (int k = 0; k < 16; ++k) {
            float2 tv = stxy[q*16 + k];
            ax = fmaf(ar[k], tv.x, ax);
            ay = fmaf(ar[k], tv.y, ay);
        }
        ax += __shfl_xor(ax, 1); ay += __shfl_xor(ay, 1);
        ax += __shfl_xor(ax, 2); ay += __shfl_xor(ay, 2);
        px = ax; py = ay;
        __syncthreads();
    }
    if (q == 0) stxy[i] = make_float2(px, py);
    if (tid < NN) { sRh[tid] = 0x7fffffff; sRo[tid] = 0x7fffffff; }
    __syncthreads();

    // radial widths: 2304 (node,angle) rays, 9 per thread, early exit each
    const float* p = pred + (size_t)b*HW;
#pragma unroll
    for (int k = 0; k < 9; ++k) {
        int pair = tid + k*256;
        int node = pair / 36, ang = pair - node*36;
        float sx = rintf(stxy[node].x);
        float sy = rintf(stxy[node].y);
        float th = (float)(10*ang) * 0.017453292519943295f;
        float c = cosf(th), s = sinf(th);
        for (int r = 1; r < Hh; ++r) {
            float rf = (float)r;
            int xi = (int)floorf(sx + rf*c);
            int yi = (int)floorf(sy + rf*s);
            bool inb = (xi >= 0) & (xi < Hh) & (yi >= 0) & (yi < Ww);
            if (!inb) { atomicMin(&sRo[node], r); break; }
            if (p[xi*Ww + yi] > 0.f) { atomicMin(&sRh[node], r); break; }
        }
    }
    __syncthreads();
    if (tid < NN) {
        int Rh = sRh[tid], Ro = sRo[tid];
        swf[tid] = (Rh != 0x7fffffff && Rh <= Ro) ? (float)(Rh - 1) : 0.f;
    }
    __syncthreads();

    if (tid < NSEG) {
        float2 P0 = stxy[tid], P1 = stxy[tid+1];
        float vx = P1.x - P0.x, vy = P1.y - P0.y;
        float vv = vx*vx + vy*vy + 1e-8f;
        float w0 = swf[tid], w1 = swf[tid+1];
        pA[b*NSEG + tid] = make_float4(P0.x, P0.y, vx, vy);
        pB[b*NSEG + tid] = make_float4(1.0f/vv, w0, w1 - w0, 0.f);
    }
}

// ------- render: 16x16 tiles, LDS-staged params, per-tile segment culling --
__global__ __launch_bounds__(256) void k_render(const float* __restrict__ pred,
                        const float4* __restrict__ pAg, const float4* __restrict__ pBg,
                        float* __restrict__ partial) {
    __shared__ float4 sSa[NSEG], sSb[NSEG];
    __shared__ int slist[NSEG];
    __shared__ int scount;
    __shared__ float red[256];
    const int b   = blockIdx.z;
    const int tid = threadIdx.x;
    const int row0 = blockIdx.x * 16, col0 = blockIdx.y * 16;
    if (tid == 0) scount = 0;
    if (tid < NSEG) {
        sSa[tid] = pAg[b*NSEG + tid];
        sSb[tid] = pBg[b*NSEG + tid];
    }
    __syncthreads();
    // cull: keep seg if center-dist - tile_radius <= max(15, w0, w1)
    if (tid < NSEG) {
        const float4 A = sSa[tid];
        const float4 Bv = sSb[tid];
        float cx = (float)row0 + 7.5f, cy = (float)col0 + 7.5f;
        float dx = cx - A.x, dy = cy - A.y;
        float t = fmaf(dy, A.w, dx*A.z) * Bv.x;
        t = fminf(fmaxf(t, 0.f), 1.f);
        float ex = fmaf(-t, A.z, dx);
        float ey = fmaf(-t, A.w, dy);
        float dc = sqrtf(ex*ex + ey*ey);
        float wmax = fmaxf(Bv.y, Bv.y + Bv.z);           // max(w0,w1)
        float lim = fmaxf(15.0f, wmax) + 10.6066f + 0.05f; // tile radius + margin
        if (dc <= lim) {
            int idx = atomicAdd(&scount, 1);
            slist[idx] = tid;
        }
    }
    __syncthreads();
    const int cnt = scount;
    const int r = tid >> 4, c = tid & 15;
    const float fx = (float)(row0 + r), fy = (float)(col0 + c);
    float m1 = 1e30f, m2 = 1e30f;
    for (int k = 0; k < cnt; ++k) {
        const int s2 = slist[k];
        const float4 A = sSa[s2];    // LDS broadcast (uniform index)
        const float4 Bv = sSb[s2];
        float dx = fx - A.x, dy = fy - A.y;
        float t = fmaf(dy, A.w, dx*A.z) * Bv.x;
        t = fminf(fmaxf(t, 0.f), 1.f);
        float ex = fmaf(-t, A.z, dx);
        float ey = fmaf(-t, A.w, dy);
        float d2 = fmaf(ex, ex, fmaf(ey, ey, 1e-12f));
        float wt = fmaf(t, Bv.z, Bv.y);
        m1 = fminf(m1, d2);
        m2 = fminf(m2, fmaf(-wt, wt, d2));
    }
    float dmap = fminf(sqrtf(m1), 15.f);
    float pm = (m2 <= 0.f) ? 1.f : 0.f;
    float pv = pred[(size_t)b*HW + (row0 + r)*Ww + (col0 + c)];
    float sg = 1.f/(1.f + expf(-pv));
    float t1 = pv - dmap, t2 = sg - pm;
    red[tid] = t1*t1 + t2*t2;
    __syncthreads();
    for (int off = 128; off > 0; off >>= 1) {
        if (tid < off) red[tid] += red[tid+off];
        __syncthreads();
    }
    if (tid == 0)
        partial[b*NTILES + blockIdx.y*TPB + blockIdx.x] = red[0];
}

__global__ void k_final(const float* __restrict__ partial, float* __restrict__ out, int n) {
    __shared__ double red[256];
    const int tid = threadIdx.x;
    double a = 0.0;
    for (int i = tid; i < n; i += 256) a += (double)partial[i];
    red[tid] = a; __syncthreads();
    for (int off = 128; off > 0; off >>= 1) {
        if (tid < off) red[tid] += red[tid+off];
        __syncthreads();
    }
    if (tid == 0) out[0] = (float)(red[0] / (double)((size_t)Bb*HW));
}

extern "C" void kernel_launch(void* const* d_in, const int* in_sizes, int n_in,
                              void* d_out, int out_size, void* d_ws, size_t ws_size,
                              hipStream_t stream) {
    const float* pred = (const float*)d_in[0];   // [4,1,384,384] f32
    const float* init = (const float*)d_in[1];   // [4,64,2] f32
    float* out = (float*)d_out;
    char* ws = (char*)d_ws;
    // ws: pA @0 | pB @4096 | partial @19456 (2304 f32) | gimg @28672
    float4* pA     = (float4*)(ws);
    float4* pB     = (float4*)(ws + 4096);
    float* partial = (float*)(ws + 19456);
    float2* gimg   = (float2*)(ws + 28672);

    k_conv  <<<dim3(12,12,4),     dim3(256), 0, stream>>>(pred, gimg);
    k_snake <<<dim3(4),           dim3(256), 0, stream>>>(gimg, pred, init, pA, pB);
    k_render<<<dim3(TPB,TPB,Bb),  dim3(256), 0, stream>>>(pred, pA, pB, partial);
    k_final <<<dim3(1),           dim3(256), 0, stream>>>(partial, out, Bb*NTILES);
}

// Round 6
// 42.062 us; speedup vs baseline: 2.9079x; 1.6424x over previous
//
#include <hip/hip_runtime.h>

#define Hh 384
#define Ww 384
#define Bb 4
#define NN 64
#define HW (Hh*Ww)
#define NSEG (NN-1)
#define TPB 24                        // 24x24 tiles of 16x16
#define NTILES (TPB*TPB)              // 576 per batch

// ---------------- compile-time Ainv = (I + 0.1*A)^-1 (banded LU, f32) ------
struct AinvT { float a[NN][NN]; };
constexpr AinvT make_ainv() {
    AinvT R{};
    float d[NN] = {}, u1[NN] = {}, u2[NN] = {}, b1[NN] = {}, L1[NN] = {}, L2[NN] = {};
    for (int k = 0; k < NN-1; ++k) { d[k] += 0.01f; d[k+1] += 0.01f; u1[k] -= 0.01f; }
    for (int k = 0; k < NN-2; ++k) {
        d[k] += 0.01f; d[k+1] += 0.04f; d[k+2] += 0.01f;
        u1[k] -= 0.02f; u1[k+1] -= 0.02f; u2[k] += 0.01f;
    }
    for (int k = 0; k < NN; ++k) {
        d[k]  = 1.0f + 0.1f*d[k];
        u1[k] = 0.1f*u1[k];
        u2[k] = 0.1f*u2[k];
        b1[k] = u1[k];
    }
    for (int k = 0; k < NN; ++k) {
        float di = d[k];
        if (k+1 < NN) { float l = b1[k]/di; L1[k] = l; d[k+1] -= l*u1[k]; if (k+2 < NN) u1[k+1] -= l*u2[k]; }
        if (k+2 < NN) { float l = u2[k]/di; L2[k] = l; b1[k+1] -= l*u1[k]; d[k+2] -= l*u2[k]; }
    }
    for (int t = 0; t < NN; ++t) {
        float y[NN] = {}, x[NN] = {};
        for (int k = 0; k < NN; ++k) {
            float v = (k == t) ? 1.0f : 0.0f;
            if (k >= 1) v -= L1[k-1]*y[k-1];
            if (k >= 2) v -= L2[k-2]*y[k-2];
            y[k] = v;
        }
        for (int kk = 0; kk < NN; ++kk) {
            int k = NN-1-kk;
            float v = y[k];
            if (k+1 < NN) v -= u1[k]*x[k+1];
            if (k+2 < NN) v -= u2[k]*x[k+2];
            x[k] = v/d[k];
        }
        for (int k = 0; k < NN; ++k) R.a[k][t] = x[k];
    }
    return R;
}
__device__ constexpr AinvT g_Ainv = make_ainv();

// ---------------- conv (separable DoG) -> gimg [B][H][W][2] ----------------
#define TILE 32
#define HALO 8
__global__ __launch_bounds__(256) void k_conv(const float* __restrict__ img,
        float2* __restrict__ gimg) {
    __shared__ float sIn[TILE+2*HALO][TILE+2*HALO];      // 48x48
    __shared__ float sColG[TILE+2*HALO][TILE];
    __shared__ float sColD[TILE+2*HALO][TILE];
    __shared__ float gtap[17], dtap[17];
    const int b  = blockIdx.z;
    const int x0 = blockIdx.x * TILE;
    const int y0 = blockIdx.y * TILE;
    const int tid = threadIdx.x;
    if (tid == 0) {
        float s = 0.f;
        for (int i = 0; i < 17; ++i) {
            float xv = (float)(i - 8);
            float e  = expf(-0.5f * (xv*0.5f)*(xv*0.5f));
            gtap[i] = e; s += e;
            dtap[i] = -(xv*0.25f) * e;
        }
        for (int i = 0; i < 17; ++i) gtap[i] /= s;
    }
    const float* im = img + b*HW;
    for (int idx = tid; idx < 48*48; idx += blockDim.x) {
        int r = idx / 48, c = idx % 48;
        int gx = x0 + r - HALO, gy = y0 + c - HALO;
        float v = 0.f;
        if (gx >= 0 && gx < Hh && gy >= 0 && gy < Ww) v = im[gx*Ww + gy];
        sIn[r][c] = v;
    }
    __syncthreads();
    for (int idx = tid; idx < 48*TILE; idx += blockDim.x) {
        int r = idx / TILE, c = idx % TILE;
        float ag = 0.f, ad = 0.f;
#pragma unroll
        for (int k = 0; k < 17; ++k) {
            float v = sIn[r][c+k];
            ag += gtap[k]*v;
            ad += dtap[k]*v;
        }
        sColG[r][c] = ag; sColD[r][c] = ad;
    }
    __syncthreads();
    float2* gg = gimg + (size_t)b*HW;
    for (int idx = tid; idx < TILE*TILE; idx += blockDim.x) {
        int xo = idx / TILE, c = idx % TILE;
        float a0 = 0.f, a1 = 0.f;
#pragma unroll
        for (int k = 0; k < 17; ++k) {
            a0 += dtap[k]*sColG[xo+k][c];
            a1 += gtap[k]*sColD[xo+k][c];
        }
        int gx = x0+xo, gy = y0+c;
        gg[gx*Ww+gy] = make_float2(10.f*a0, 10.f*a1);
    }
}

// ------- snake (20 steps, const Ainv) + lockstep widths + segment prep -----
__global__ __launch_bounds__(256) void k_snake(const float2* __restrict__ gimg,
                        const float* __restrict__ pred, const float* __restrict__ init,
                        float4* __restrict__ pA, float4* __restrict__ pB) {
    __shared__ float2 stxy[NN];
    __shared__ float swf[NN];
    const int b = blockIdx.x;
    const int tid = threadIdx.x;
    const int i = tid >> 2;
    const int q = tid & 3;

    // 16 Ainv coefficients per thread from the compile-time table
    float ar[16];
#pragma unroll
    for (int k = 0; k < 16; ++k) ar[k] = g_Ainv.a[i][q*16 + k];

    float px = init[(b*NN + i)*2 + 0];
    float py = init[(b*NN + i)*2 + 1];
    const float2* g = gimg + (size_t)b*HW;

    for (int s = 0; s < 20; ++s) {
        float x = fminf(fmaxf(px, 0.f), (float)(Hh-1));
        float y = fminf(fmaxf(py, 0.f), (float)(Ww-1));
        int x0i = (int)floorf(x); x0i = min(max(x0i, 0), Hh-2);
        int y0i = (int)floorf(y); y0i = min(max(y0i, 0), Ww-2);
        float fx = x - (float)x0i, fy = y - (float)y0i;
        int base = x0i*Ww + y0i;
        float2 v00 = g[base],    v01 = g[base+1];
        float2 v10 = g[base+Ww], v11 = g[base+Ww+1];
        float t0x = v00.x*(1.f-fy) + v01.x*fy;
        float t0y = v00.y*(1.f-fy) + v01.y*fy;
        float b0x = v10.x*(1.f-fy) + v11.x*fy;
        float b0y = v10.y*(1.f-fy) + v11.y*fy;
        float f0 = t0x*(1.f-fx) + b0x*fx;
        float f1 = t0y*(1.f-fx) + b0y*fx;
        if (q == 0) stxy[i] = make_float2(px + 0.1f*f0, py + 0.1f*f1);
        __syncthreads();
        float ax = 0.f, ay = 0.f;
#pragma unroll
        for (int k = 0; k < 16; ++k) {
            float2 tv = stxy[q*16 + k];
            ax = fmaf(ar[k], tv.x, ax);
            ay = fmaf(ar[k], tv.y, ay);
        }
        ax += __shfl_xor(ax, 1); ay += __shfl_xor(ay, 1);
        ax += __shfl_xor(ax, 2); ay += __shfl_xor(ay, 2);
        px = ax; py = ay;
        __syncthreads();
    }
    if (q == 0) stxy[i] = make_float2(px, py);
    __syncthreads();

    // ---- lockstep radial widths: wave per node-round, ballot early exit ----
    const float* p = pred + (size_t)b*HW;
    const int wid  = tid >> 6;          // wave 0..3
    const int lane = tid & 63;
    const bool active = lane < 36;
    const float theta = (float)(10*lane) * 0.017453292519943295f;
    const float cth = cosf(theta), sth = sinf(theta);
    for (int nc = 0; nc < 16; ++nc) {
        const int node = wid*16 + nc;
        const float sx = rintf(stxy[node].x);
        const float sy = rintf(stxy[node].y);
        float w = 0.f;
        for (int r = 1; r < Hh; ++r) {
            float rf = (float)r;
            bool hit = false, oob = false;
            if (active) {
                int xi = (int)floorf(sx + rf*cth);
                int yi = (int)floorf(sy + rf*sth);
                bool inb = (xi >= 0) & (xi < Hh) & (yi >= 0) & (yi < Ww);
                if (!inb) oob = true;
                else if (p[xi*Ww + yi] > 0.f) hit = true;   // sigmoid(-p)<0.5 <=> p>0
            }
            unsigned long long mh = __ballot(hit);
            unsigned long long mo = __ballot(oob);
            if (mh | mo) { w = mh ? (rf - 1.f) : 0.f; break; }
        }
        if (lane == 0) swf[node] = w;
    }
    __syncthreads();

    // ---- segment prep ----
    if (tid < NSEG) {
        float2 P0 = stxy[tid], P1 = stxy[tid+1];
        float vx = P1.x - P0.x, vy = P1.y - P0.y;
        float vv = vx*vx + vy*vy + 1e-8f;
        float w0 = swf[tid], w1 = swf[tid+1];
        pA[b*NSEG + tid] = make_float4(P0.x, P0.y, vx, vy);
        pB[b*NSEG + tid] = make_float4(1.0f/vv, w0, w1 - w0, 0.f);
    }
}

// ------- render: 16x16 tiles, LDS-staged params, per-tile segment culling --
__global__ __launch_bounds__(256) void k_render(const float* __restrict__ pred,
                        const float4* __restrict__ pAg, const float4* __restrict__ pBg,
                        float* __restrict__ partial) {
    __shared__ float4 sSa[NSEG], sSb[NSEG];
    __shared__ int slist[NSEG];
    __shared__ int scount;
    __shared__ float red[256];
    const int b   = blockIdx.z;
    const int tid = threadIdx.x;
    const int row0 = blockIdx.x * 16, col0 = blockIdx.y * 16;
    if (tid == 0) scount = 0;
    if (tid < NSEG) {
        sSa[tid] = pAg[b*NSEG + tid];
        sSb[tid] = pBg[b*NSEG + tid];
    }
    __syncthreads();
    if (tid < NSEG) {
        const float4 A = sSa[tid];
        const float4 Bv = sSb[tid];
        float cx = (float)row0 + 7.5f, cy = (float)col0 + 7.5f;
        float dx = cx - A.x, dy = cy - A.y;
        float t = fmaf(dy, A.w, dx*A.z) * Bv.x;
        t = fminf(fmaxf(t, 0.f), 1.f);
        float ex = fmaf(-t, A.z, dx);
        float ey = fmaf(-t, A.w, dy);
        float dc = sqrtf(ex*ex + ey*ey);
        float wmax = fmaxf(Bv.y, Bv.y + Bv.z);
        float lim = fmaxf(15.0f, wmax) + 10.6066f + 0.05f;
        if (dc <= lim) {
            int idx = atomicAdd(&scount, 1);
            slist[idx] = tid;
        }
    }
    __syncthreads();
    const int cnt = scount;
    const int r = tid >> 4, c = tid & 15;
    const float fx = (float)(row0 + r), fy = (float)(col0 + c);
    float m1 = 1e30f, m2 = 1e30f;
    for (int k = 0; k < cnt; ++k) {
        const int s2 = slist[k];
        const float4 A = sSa[s2];
        const float4 Bv = sSb[s2];
        float dx = fx - A.x, dy = fy - A.y;
        float t = fmaf(dy, A.w, dx*A.z) * Bv.x;
        t = fminf(fmaxf(t, 0.f), 1.f);
        float ex = fmaf(-t, A.z, dx);
        float ey = fmaf(-t, A.w, dy);
        float d2 = fmaf(ex, ex, fmaf(ey, ey, 1e-12f));
        float wt = fmaf(t, Bv.z, Bv.y);
        m1 = fminf(m1, d2);
        m2 = fminf(m2, fmaf(-wt, wt, d2));
    }
    float dmap = fminf(sqrtf(m1), 15.f);
    float pm = (m2 <= 0.f) ? 1.f : 0.f;
    float pv = pred[(size_t)b*HW + (row0 + r)*Ww + (col0 + c)];
    float sg = 1.f/(1.f + expf(-pv));
    float t1 = pv - dmap, t2 = sg - pm;
    red[tid] = t1*t1 + t2*t2;
    __syncthreads();
    for (int off = 128; off > 0; off >>= 1) {
        if (tid < off) red[tid] += red[tid+off];
        __syncthreads();
    }
    if (tid == 0)
        partial[b*NTILES + blockIdx.y*TPB + blockIdx.x] = red[0];
}

__global__ void k_final(const float* __restrict__ partial, float* __restrict__ out, int n) {
    __shared__ double red[256];
    const int tid = threadIdx.x;
    double a = 0.0;
    for (int i = tid; i < n; i += 256) a += (double)partial[i];
    red[tid] = a; __syncthreads();
    for (int off = 128; off > 0; off >>= 1) {
        if (tid < off) red[tid] += red[tid+off];
        __syncthreads();
    }
    if (tid == 0) out[0] = (float)(red[0] / (double)((size_t)Bb*HW));
}

extern "C" void kernel_launch(void* const* d_in, const int* in_sizes, int n_in,
                              void* d_out, int out_size, void* d_ws, size_t ws_size,
                              hipStream_t stream) {
    const float* pred = (const float*)d_in[0];   // [4,1,384,384] f32
    const float* init = (const float*)d_in[1];   // [4,64,2] f32
    float* out = (float*)d_out;
    char* ws = (char*)d_ws;
    // ws: pA @0 | pB @4096 | partial @19456 (2304 f32) | gimg @28672
    float4* pA     = (float4*)(ws);
    float4* pB     = (float4*)(ws + 4096);
    float* partial = (float*)(ws + 19456);
    float2* gimg   = (float2*)(ws + 28672);

    k_conv  <<<dim3(12,12,4),     dim3(256), 0, stream>>>(pred, gimg);
    k_snake <<<dim3(4),           dim3(256), 0, stream>>>(gimg, pred, init, pA, pB);
    k_render<<<dim3(TPB,TPB,Bb),  dim3(256), 0, stream>>>(pred, pA, pB, partial);
    k_final <<<dim3(1),           dim3(256), 0, stream>>>(partial, out, Bb*NTILES);
}